// Round 9
// baseline (333.259 us; speedup 1.0000x reference)
//
#include <hip/hip_runtime.h>

// GCNEncoder: 2-layer GCN (sym-norm, self-loops) + LayerNorm. N=100000, E=1600000, D=128.
// Round 9. r8 (fill_sort) landed as predicted: 373->314us. gather_ln still top:
// 75us, FETCH 196MB (compulsory), VALUBusy 44%, HBM 42% -> neither pipe saturated =
// VMEM-issue/latency bound (3 VMEM + ~9 VALU per edge). This round: dwordx4 gather.
// Lane covers 8 cols for edge-subgroup lane>>4: per 8 edges 6 VMEM (vs 24), ~45 VALU
// (vs ~72). Cross-lane merge via shfl_xor(16,32); LN reduces over 64 lanes (/512).
// Everything else identical to r8.

#define N_NODES 100000
#define N_EDGES 1600000
#define NBLK_N  391          // ceil(N_NODES/256)
#define NB      196          // buckets = ceil(N/512)
#define BKT_CAP 8960         // mean 8192 + ~8.5 sigma, overflow-guarded
#define BIN_GRID 391         // binning blocks, 4096 edges each
#define GEMM_GRID 1563       // ceil(N/64)

typedef unsigned int  u32;
typedef unsigned short u16;
typedef unsigned char u8;
typedef __attribute__((ext_vector_type(8))) short bf16x8;
typedef __attribute__((ext_vector_type(4))) float f32x4;
typedef __attribute__((ext_vector_type(4))) u32 u32x4;

__device__ __forceinline__ float bflo(u32 u){ return __uint_as_float(u << 16); }
__device__ __forceinline__ float bfhi(u32 u){ return __uint_as_float(u & 0xFFFF0000u); }
__device__ __forceinline__ u32 f2b(float f){
  u32 u = __float_as_uint(f);
  return (u + 0x7FFFu + ((u >> 16) & 1u)) >> 16;   // RNE
}
__device__ __forceinline__ u32 pack2(float a, float b){ return f2b(a) | (f2b(b) << 16); }
__device__ __forceinline__ u32 clampN(int s){
  u32 u = (u32)s;
  return (u < (u32)N_NODES) ? u : (u32)(N_NODES - 1);
}

// ---------------- detect (edge width) + zero bucket_fill, one dispatch ----------------
__global__ __launch_bounds__(256) void detect_init(const int* __restrict__ ei,
                                                   int* __restrict__ flags,
                                                   u32* __restrict__ bucket_fill){
  int t = threadIdx.x;
  if (t < NB) bucket_fill[t] = 0;
  if (t < 64){
    int nzodd = (ei[2 * t + 1] != 0) ? 1 : 0;
    #pragma unroll
    for (int o = 32; o > 0; o >>= 1) nzodd += __shfl_xor(nzodd, o, 64);
    if (t == 0) flags[1] = (nzodd == 0) ? 1 : 0;   // 1 => int64
  }
}

// ---------------- GEMM device bodies (16x16x32 bf16 MFMA, bf16 H output) ----------------
// A-frag: m=lane&15, k=(lane>>4)*8+j   B-frag: n=lane&15, k=(lane>>4)*8+j
// D: col=lane&15, row=(lane>>4)*4+r.  W (fp32) -> bf16 fragment-major LDS.

__device__ __forceinline__ void build_wfrag(u16* wfrag, const float* __restrict__ W,
                                            int tid){
  #pragma unroll
  for (int i = 0; i < 8; ++i){
    int fid   = tid + i * 256;
    int lane  = fid & 63;
    int kb    = (fid >> 6) & 3;
    int ntile = fid >> 8;
    int n  = ntile * 16 + (lane & 15);
    int k0 = kb * 32 + (lane >> 4) * 8;
    u16 tmp[8];
    #pragma unroll
    for (int j = 0; j < 8; ++j) tmp[j] = (u16)f2b(W[(k0 + j) * 128 + n]);
    *(bf16x8*)(wfrag + (size_t)fid * 8) = *(const bf16x8*)tmp;
  }
}

__device__ __forceinline__ void gemm_tail(const u16* wfrag, const bf16x8 afrag[4],
                                          int rowbase, int lane,
                                          u16* __restrict__ Hout, int nrows){
  const int m = lane & 15, q = lane >> 4;
  f32x4 acc[8];
  #pragma unroll
  for (int n = 0; n < 8; ++n) acc[n] = (f32x4){0.f, 0.f, 0.f, 0.f};
  #pragma unroll
  for (int n = 0; n < 8; ++n){
    #pragma unroll
    for (int kb = 0; kb < 4; ++kb){
      bf16x8 bfrag = *(const bf16x8*)(wfrag + ((size_t)(n * 4 + kb) * 64 + lane) * 8);
      acc[n] = __builtin_amdgcn_mfma_f32_16x16x32_bf16(afrag[kb], bfrag, acc[n], 0, 0, 0);
    }
  }
  #pragma unroll
  for (int r = 0; r < 4; ++r){
    int orow = rowbase + q * 4 + r;
    if (orow < nrows){
      u16* Or = Hout + (size_t)orow * 128 + m;
      #pragma unroll
      for (int n = 0; n < 8; ++n) Or[n * 16] = (u16)f2b(acc[n][r]);
    }
  }
}

__device__ __forceinline__ void gemm_f32_body(u16* wfrag, const float* __restrict__ A,
                                              const float* __restrict__ W,
                                              u16* __restrict__ Hout, int nrows, int bid){
  build_wfrag(wfrag, W, threadIdx.x);
  __syncthreads();
  const int lane = threadIdx.x & 63;
  const int wv   = threadIdx.x >> 6;
  const int rowbase = bid * 64 + wv * 16;
  const int row  = rowbase + (lane & 15);
  const int rowc = (row < nrows) ? row : (nrows - 1);
  const int q    = lane >> 4;
  bf16x8 afrag[4];
  const float* Ar = A + (size_t)rowc * 128;
  #pragma unroll
  for (int kb = 0; kb < 4; ++kb){
    f32x4 p0 = *(const f32x4*)(Ar + kb * 32 + q * 8);
    f32x4 p1 = *(const f32x4*)(Ar + kb * 32 + q * 8 + 4);
    bf16x8 f;
    f[0] = (short)f2b(p0[0]); f[1] = (short)f2b(p0[1]);
    f[2] = (short)f2b(p0[2]); f[3] = (short)f2b(p0[3]);
    f[4] = (short)f2b(p1[0]); f[5] = (short)f2b(p1[1]);
    f[6] = (short)f2b(p1[2]); f[7] = (short)f2b(p1[3]);
    afrag[kb] = f;
  }
  gemm_tail(wfrag, afrag, rowbase, lane, Hout, nrows);
}

__device__ __forceinline__ void gemm_bf16_body(u16* wfrag, const u16* __restrict__ A,
                                               const float* __restrict__ W,
                                               u16* __restrict__ Hout, int nrows, int bid){
  build_wfrag(wfrag, W, threadIdx.x);
  __syncthreads();
  const int lane = threadIdx.x & 63;
  const int wv   = threadIdx.x >> 6;
  const int rowbase = bid * 64 + wv * 16;
  const int row  = rowbase + (lane & 15);
  const int rowc = (row < nrows) ? row : (nrows - 1);
  const int q    = lane >> 4;
  bf16x8 afrag[4];
  const u16* Ar = A + (size_t)rowc * 128;
  #pragma unroll
  for (int kb = 0; kb < 4; ++kb)
    afrag[kb] = *(const bf16x8*)(Ar + kb * 32 + q * 8);
  gemm_tail(wfrag, afrag, rowbase, lane, Hout, nrows);
}

// ---------------- binning body: edges -> per-bucket-contiguous packed buffer ----------------

__device__ __forceinline__ void binA_body(u32* cnt /*LDS 512 u32*/,
                                          const int* __restrict__ ei,
                                          const int* __restrict__ flags,
                                          u32* __restrict__ binned,
                                          u32* __restrict__ bucket_fill, int bb){
  u32* gbase = cnt + 256;
  const int tid = threadIdx.x;
  cnt[tid] = 0;
  __syncthreads();
  const int i64  = flags[1];
  const int base = bb * 4096;
  u32 pk[16], rk[16], bk[16];
  #pragma unroll
  for (int j = 0; j < 16; ++j){
    int e = base + tid + j * 256;
    bk[j] = 0xFFFFFFFFu;
    if (e < N_EDGES){
      int dsti = i64 ? ei[2 * N_EDGES + 2 * e] : ei[N_EDGES + e];
      int srci = i64 ? ei[2 * e]               : ei[e];
      u32 ud = clampN(dsti), us = clampN(srci);
      u32 b = ud >> 9;
      bk[j] = b;
      pk[j] = us | ((ud & 511u) << 17);
      rk[j] = atomicAdd(&cnt[b], 1u);
    }
  }
  __syncthreads();
  u32 c = cnt[tid];
  u32 old = 0;
  if (c) old = atomicAdd(&bucket_fill[tid < NB ? tid : 0], tid < NB ? c : 0u);
  gbase[tid] = old;
  __syncthreads();
  #pragma unroll
  for (int j = 0; j < 16; ++j){
    if (bk[j] != 0xFFFFFFFFu){
      u32 idx = gbase[bk[j]] + rk[j];
      if (idx < BKT_CAP) binned[(size_t)bk[j] * BKT_CAP + idx] = pk[j];
    }
  }
}

// ---------------- fused: gemm1 (blocks < GEMM_GRID) + binning (rest) ----------------

__global__ __launch_bounds__(256) void fused_gemm_bin(const float* __restrict__ A,
                                                      const float* __restrict__ W,
                                                      u16* __restrict__ Hout,
                                                      const int* __restrict__ ei,
                                                      const int* __restrict__ flags,
                                                      u32* __restrict__ binned,
                                                      u32* __restrict__ bucket_fill){
  __shared__ u16 smem[16384];                  // 32 KB
  if (blockIdx.x < GEMM_GRID){
    gemm_f32_body(smem, A, W, Hout, N_NODES, blockIdx.x);
  } else {
    binA_body((u32*)smem, ei, flags, binned, bucket_fill, blockIdx.x - GEMM_GRID);
  }
}

// standalone gemms (fallback path / layer 2)
__global__ __launch_bounds__(256) void gemm_f32in(const float* __restrict__ A,
                                                  const float* __restrict__ W,
                                                  u16* __restrict__ Hout){
  __shared__ u16 smem[16384];
  gemm_f32_body(smem, A, W, Hout, N_NODES, blockIdx.x);
}
__global__ __launch_bounds__(256) void gemm_bf16in(const u16* __restrict__ A,
                                                   const float* __restrict__ W,
                                                   u16* __restrict__ Hout){
  __shared__ u16 smem[16384];
  gemm_bf16_body(smem, A, W, Hout, N_NODES, blockIdx.x);
}

// ---------------- fill_sort: one block per bucket (offs + dinv + sorted srclist) ----------------

__global__ __launch_bounds__(256) void fill_sort(const u32* __restrict__ binned,
                                                 const u32* __restrict__ bucket_fill,
                                                 int* __restrict__ offs,
                                                 float* __restrict__ dinv,
                                                 int* __restrict__ srclist){
  __shared__ u32 cnt[512];
  __shared__ u32 sc[512];
  __shared__ u32 red[256];
  const int b   = blockIdx.x;
  const int tid = threadIdx.x;
  cnt[tid] = 0; cnt[tid + 256] = 0;
  __syncthreads();

  u32 n = bucket_fill[b]; if (n > BKT_CAP) n = BKT_CAP;
  const u32* eb = binned + (size_t)b * BKT_CAP;

  for (u32 i = tid; i < n; i += 256)
    atomicAdd(&cnt[eb[i] >> 17], 1u);

  u32 v = 0;
  if (tid < b && tid < NB){
    u32 f = bucket_fill[tid];
    v = (f > BKT_CAP) ? BKT_CAP : f;
  }
  red[tid] = v;
  __syncthreads();
  for (int o = 128; o > 0; o >>= 1){
    if (tid < o) red[tid] += red[tid + o];
    __syncthreads();
  }
  const u32 base = red[0];
  __syncthreads();

  u32 pair = cnt[2 * tid] + cnt[2 * tid + 1];
  red[tid] = pair;
  __syncthreads();
  for (int o = 1; o < 256; o <<= 1){
    u32 add = (tid >= o) ? red[tid - o] : 0;
    __syncthreads();
    red[tid] += add;
    __syncthreads();
  }
  u32 pex = red[tid] - pair;
  sc[2 * tid]     = pex;
  sc[2 * tid + 1] = pex + cnt[2 * tid];
  __syncthreads();

  const u32 basenode = (u32)b << 9;
  #pragma unroll
  for (int h = 0; h < 2; ++h){
    u32 l = tid + h * 256;
    u32 node = basenode + l;
    if (node < (u32)N_NODES){
      offs[node] = (int)(base + sc[l]);
      dinv[node] = rsqrtf((float)cnt[l] + 1.0f);
    }
  }
  if (b == NB - 1 && tid == 0) offs[N_NODES] = (int)(base + n);

  __syncthreads();
  cnt[tid] = 0; cnt[tid + 256] = 0;
  __syncthreads();
  for (u32 i = tid; i < n; i += 256){
    u32 pk = eb[i];
    u32 d  = pk >> 17;
    u32 r  = atomicAdd(&cnt[d], 1u);
    srclist[base + sc[d] + r] = (int)(pk & 0x1FFFFu);
  }
}

// ---------------- fallback CSR kernels (round-5 path, used if ws too small) ----------------

__global__ __launch_bounds__(256) void count_deg(const int* __restrict__ ei,
                                                 const int* __restrict__ flags,
                                                 int* __restrict__ deg){
  int e   = blockIdx.x * 256 + threadIdx.x;
  int i64 = flags[1];
  int dst = i64 ? ei[2 * N_EDGES + 2 * e] : ei[N_EDGES + e];
  if ((unsigned)dst < (unsigned)N_NODES) atomicAdd(&deg[dst], 1);
}

__global__ __launch_bounds__(256) void fill_edges(const int* __restrict__ ei,
                                                  const int* __restrict__ flags,
                                                  int* __restrict__ woff,
                                                  int* __restrict__ srclist){
  int e   = blockIdx.x * 256 + threadIdx.x;
  int i64 = flags[1];
  int dst = i64 ? ei[2 * N_EDGES + 2 * e] : ei[N_EDGES + e];
  int src = i64 ? ei[2 * e]               : ei[e];
  if ((unsigned)dst < (unsigned)N_NODES){
    int p = atomicAdd(&woff[dst], 1);
    if ((unsigned)p < (unsigned)N_EDGES) srclist[p] = clampN(src);
  }
}

__global__ __launch_bounds__(256) void scan1(const int* __restrict__ deg,
                                             int* __restrict__ offs,
                                             int* __restrict__ bsum,
                                             float* __restrict__ dinv){
  __shared__ int sh[256];
  int t = threadIdx.x;
  int i = blockIdx.x * 256 + t;
  int v = (i < N_NODES) ? deg[i] : 0;
  if (i < N_NODES) dinv[i] = rsqrtf((float)v + 1.0f);
  sh[t] = v;
  __syncthreads();
  for (int o = 1; o < 256; o <<= 1){
    int add = (t >= o) ? sh[t - o] : 0;
    __syncthreads();
    sh[t] += add;
    __syncthreads();
  }
  if (i < N_NODES) offs[i] = sh[t] - v;
  if (t == 255)    bsum[blockIdx.x] = sh[255];
}

__global__ __launch_bounds__(512) void scan2(const int* __restrict__ bsum,
                                             int* __restrict__ bofs){
  __shared__ int sh[512];
  int t = threadIdx.x;
  int v = (t < NBLK_N) ? bsum[t] : 0;
  sh[t] = v;
  __syncthreads();
  for (int o = 1; o < 512; o <<= 1){
    int add = (t >= o) ? sh[t - o] : 0;
    __syncthreads();
    sh[t] += add;
    __syncthreads();
  }
  if (t < NBLK_N) bofs[t] = sh[t] - v;
}

__global__ __launch_bounds__(256) void finalize_offs(int* __restrict__ offs,
                                                     const int* __restrict__ bofs,
                                                     int* __restrict__ woff){
  int i = blockIdx.x * 256 + threadIdx.x;
  if (i < N_NODES){
    int o = offs[i] + bofs[blockIdx.x];
    offs[i] = o;
    woff[i] = o;
  }
  if (i == 0) offs[N_NODES] = N_EDGES;
}

// ---------------- gathers: 1 wave/node; lane = 8 cols x edge-subgroup(lane>>4) ----------------
// Per 8 edges: 6 VMEM (2 srcl, 2 dinv, 2 H-dwordx4) + ~45 VALU. Tail via clamped
// index + zero weight (branchless). srclist entries pre-clamped < N at binning.

__global__ __launch_bounds__(256) void gather_relu(const int* __restrict__ offs,
                                                   const int* __restrict__ srcl,
                                                   const u32* __restrict__ H,
                                                   const float* __restrict__ dinv,
                                                   const float* __restrict__ bias,
                                                   u32* __restrict__ X2){
  const int node = blockIdx.x * 4 + (threadIdx.x >> 6);
  const int lane = threadIdx.x & 63;
  const int grp  = lane >> 4;
  const int cq   = (lane & 15) * 4;      // first u32 of this lane's 8 cols
  int beg = offs[node], end = offs[node + 1];
  if (end > N_EDGES) end = N_EDGES;
  if (beg < 0 || beg > end) beg = end;

  float a[8] = {0,0,0,0,0,0,0,0};
  float c[8] = {0,0,0,0,0,0,0,0};
  for (int e = beg; e < end; e += 8){
    int e0 = e + grp, e1 = e + 4 + grp;
    int e0c = (e0 < end) ? e0 : (end - 1);
    int e1c = (e1 < end) ? e1 : (end - 1);
    u32 s0 = (u32)srcl[e0c], s1 = (u32)srcl[e1c];
    float w0 = (e0 < end) ? dinv[s0] : 0.f;
    float w1 = (e1 < end) ? dinv[s1] : 0.f;
    u32x4 h0 = *(const u32x4*)(H + (size_t)s0 * 64 + cq);
    u32x4 h1 = *(const u32x4*)(H + (size_t)s1 * 64 + cq);
    #pragma unroll
    for (int k = 0; k < 4; ++k){
      a[2*k]   = fmaf(w0, bflo(h0[k]), a[2*k]);
      a[2*k+1] = fmaf(w0, bfhi(h0[k]), a[2*k+1]);
      c[2*k]   = fmaf(w1, bflo(h1[k]), c[2*k]);
      c[2*k+1] = fmaf(w1, bfhi(h1[k]), c[2*k+1]);
    }
  }
  #pragma unroll
  for (int k = 0; k < 8; ++k){
    a[k] += c[k];
    a[k] += __shfl_xor(a[k], 16, 64);
    a[k] += __shfl_xor(a[k], 32, 64);
  }

  float di = dinv[node];
  u32x4 hs = *(const u32x4*)(H + (size_t)node * 64 + cq);
  f32x4 bA = *(const f32x4*)(bias + 2 * cq);
  f32x4 bB = *(const f32x4*)(bias + 2 * cq + 4);
  float bb[8] = {bA[0],bA[1],bA[2],bA[3],bB[0],bB[1],bB[2],bB[3]};
  u32 outp[4];
  #pragma unroll
  for (int k = 0; k < 4; ++k){
    float vl = fmaf(a[2*k],   di, fmaf(bflo(hs[k]), di*di, bb[2*k]));
    float vh = fmaf(a[2*k+1], di, fmaf(bfhi(hs[k]), di*di, bb[2*k+1]));
    outp[k] = pack2(fmaxf(vl, 0.f), fmaxf(vh, 0.f));
  }
  if (grp == 0)
    *(u32x4*)(X2 + (size_t)node * 64 + cq) = (u32x4){outp[0],outp[1],outp[2],outp[3]};
}

__global__ __launch_bounds__(256) void gather_ln(const int* __restrict__ offs,
                                                 const int* __restrict__ srcl,
                                                 const u32* __restrict__ H,
                                                 const float* __restrict__ dinv,
                                                 const float* __restrict__ bias,
                                                 const float* __restrict__ gamma,
                                                 const float* __restrict__ beta,
                                                 float* __restrict__ out){
  const int node = blockIdx.x * 4 + (threadIdx.x >> 6);
  const int lane = threadIdx.x & 63;
  const int grp  = lane >> 4;
  const int cq   = (lane & 15) * 4;
  int beg = offs[node], end = offs[node + 1];
  if (end > N_EDGES) end = N_EDGES;
  if (beg < 0 || beg > end) beg = end;

  float a[8] = {0,0,0,0,0,0,0,0};
  float c[8] = {0,0,0,0,0,0,0,0};
  for (int e = beg; e < end; e += 8){
    int e0 = e + grp, e1 = e + 4 + grp;
    int e0c = (e0 < end) ? e0 : (end - 1);
    int e1c = (e1 < end) ? e1 : (end - 1);
    u32 s0 = (u32)srcl[e0c], s1 = (u32)srcl[e1c];
    float w0 = (e0 < end) ? dinv[s0] : 0.f;
    float w1 = (e1 < end) ? dinv[s1] : 0.f;
    u32x4 h0 = *(const u32x4*)(H + (size_t)s0 * 64 + cq);
    u32x4 h1 = *(const u32x4*)(H + (size_t)s1 * 64 + cq);
    #pragma unroll
    for (int k = 0; k < 4; ++k){
      a[2*k]   = fmaf(w0, bflo(h0[k]), a[2*k]);
      a[2*k+1] = fmaf(w0, bfhi(h0[k]), a[2*k+1]);
      c[2*k]   = fmaf(w1, bflo(h1[k]), c[2*k]);
      c[2*k+1] = fmaf(w1, bfhi(h1[k]), c[2*k+1]);
    }
  }
  #pragma unroll
  for (int k = 0; k < 8; ++k){
    a[k] += c[k];
    a[k] += __shfl_xor(a[k], 16, 64);
    a[k] += __shfl_xor(a[k], 32, 64);
  }

  float di = dinv[node];
  u32x4 hs = *(const u32x4*)(H + (size_t)node * 64 + cq);
  f32x4 bA = *(const f32x4*)(bias + 2 * cq);
  f32x4 bB = *(const f32x4*)(bias + 2 * cq + 4);
  float bb[8] = {bA[0],bA[1],bA[2],bA[3],bB[0],bB[1],bB[2],bB[3]};
  float vv[8];
  #pragma unroll
  for (int k = 0; k < 4; ++k){
    vv[2*k]   = fmaf(a[2*k],   di, fmaf(bflo(hs[k]), di*di, bb[2*k]));
    vv[2*k+1] = fmaf(a[2*k+1], di, fmaf(bfhi(hs[k]), di*di, bb[2*k+1]));
  }

  // LayerNorm: per-lane partial over its 8 cols; 64-lane reduce counts each col 4x.
  float s2 = 0.f;
  #pragma unroll
  for (int k = 0; k < 8; ++k) s2 += vv[k];
  #pragma unroll
  for (int o = 32; o > 0; o >>= 1) s2 += __shfl_xor(s2, o, 64);
  float mu = s2 * (1.0f / 512.0f);
  float dd[8];
  float qq = 0.f;
  #pragma unroll
  for (int k = 0; k < 8; ++k){ dd[k] = vv[k] - mu; qq += dd[k] * dd[k]; }
  #pragma unroll
  for (int o = 32; o > 0; o >>= 1) qq += __shfl_xor(qq, o, 64);
  float rr = rsqrtf(qq * (1.0f / 512.0f) + 1e-5f);

  f32x4 gA = *(const f32x4*)(gamma + 2 * cq);
  f32x4 gB = *(const f32x4*)(gamma + 2 * cq + 4);
  f32x4 tA = *(const f32x4*)(beta + 2 * cq);
  f32x4 tB = *(const f32x4*)(beta + 2 * cq + 4);
  float gg[8] = {gA[0],gA[1],gA[2],gA[3],gB[0],gB[1],gB[2],gB[3]};
  float tt[8] = {tA[0],tA[1],tA[2],tA[3],tB[0],tB[1],tB[2],tB[3]};
  if (grp < 2){
    f32x4 o4;
    #pragma unroll
    for (int k = 0; k < 4; ++k){
      int idx = grp * 4 + k;
      o4[k] = fmaf(dd[idx] * rr, gg[idx], tt[idx]);
    }
    *(f32x4*)(out + (size_t)node * 128 + 2 * cq + grp * 4) = o4;
  }
}

// ---------------- launch ----------------

extern "C" void kernel_launch(void* const* d_in, const int* in_sizes, int n_in,
                              void* d_out, int out_size, void* d_ws, size_t ws_size,
                              hipStream_t stream){
  const float* x  = (const float*)d_in[0];
  const int*   ei = (const int*)d_in[1];
  const float* W1 = (const float*)d_in[2];
  const float* b1 = (const float*)d_in[3];
  const float* W2 = (const float*)d_in[4];
  const float* b2 = (const float*)d_in[5];
  const float* gm = (const float*)d_in[6];
  const float* bt = (const float*)d_in[7];

  char* ws = (char*)d_ws;
  size_t off = 0;
  auto carve = [&](size_t bytes) -> void* {
    void* p = ws + off;
    off = (off + bytes + 255) & ~(size_t)255;
    return p;
  };
  int*   flags       = (int*)  carve(64);
  u32*   bucket_fill = (u32*)  carve(NB * 4);
  int*   offs        = (int*)  carve((size_t)(N_NODES + 1) * 4);
  float* dinv        = (float*)carve((size_t)N_NODES * 4);
  int*   srclist     = (int*)  carve((size_t)N_EDGES * 4);
  int*   deg         = (int*)  carve((size_t)N_NODES * 4);   // fallback only (woff)
  int*   bsum        = (int*)  carve(2048);                  // fallback only
  int*   bofs        = (int*)  carve(2048);                  // fallback only

  size_t bin_bytes = (size_t)NB * BKT_CAP * 4;               // 7.02 MB
  u32* binned = (u32*)carve(bin_bytes);
  bool use_binned = (ws_size >= off);
  if (!use_binned) off = (size_t)((char*)binned - ws);       // un-carve

  size_t h_bytes = (size_t)N_NODES * 128 * 2;                // 25.6 MB (bf16)
  u32* H1 = (u32*)d_out;
  u32* X2 = (u32*)d_out + 6400000;
  u32* H2 = (ws_size >= off + h_bytes) ? (u32*)carve(h_bytes) : (u32*)d_in[0];

  detect_init<<<1, 256, 0, stream>>>(ei, flags, bucket_fill);

  if (use_binned){
    fused_gemm_bin<<<GEMM_GRID + BIN_GRID, 256, 0, stream>>>(x, W1, (u16*)H1, ei, flags,
                                                             binned, bucket_fill);
    fill_sort     <<<NB, 256, 0, stream>>>(binned, bucket_fill, offs, dinv, srclist);
  } else {
    hipMemsetAsync(deg, 0, (size_t)N_NODES * 4, stream);
    count_deg     <<<N_EDGES / 256, 256, 0, stream>>>(ei, flags, deg);
    scan1         <<<NBLK_N,        256, 0, stream>>>(deg, offs, bsum, dinv);
    scan2         <<<1,             512, 0, stream>>>(bsum, bofs);
    finalize_offs <<<NBLK_N,        256, 0, stream>>>(offs, bofs, deg /*woff*/);
    fill_edges    <<<N_EDGES / 256, 256, 0, stream>>>(ei, flags, deg /*woff*/, srclist);
    gemm_f32in    <<<GEMM_GRID,     256, 0, stream>>>(x, W1, (u16*)H1);
  }

  gather_relu <<<N_NODES / 4, 256, 0, stream>>>(offs, srclist, H1, dinv, b1, X2);
  gemm_bf16in <<<GEMM_GRID,   256, 0, stream>>>((const u16*)X2, W2, (u16*)H2);
  gather_ln   <<<N_NODES / 4, 256, 0, stream>>>(offs, srclist, H2, dinv, b2, gm, bt,
                                                (float*)d_out);
}

// Round 10
// 312.307 us; speedup vs baseline: 1.0671x; 1.0671x over previous
//
#include <hip/hip_runtime.h>

// GCNEncoder: 2-layer GCN (sym-norm, self-loops) + LayerNorm. N=100000, E=1600000, D=128.
// Round 10. r9 dwordx4 gather REGRESSED (75->91us, VALU 44->71%): per-lane tail
// predication + divergent addr math ~doubled VALU work -> gather was never VMEM-issue
// bound. Revised model: random-access L2-miss bandwidth to L3 (~3.4 TB/s TCC traffic,
// 25.6MB working set vs 4MiB/XCD L2, FETCH at compulsory 196MB; unroll-insensitive
// r6==r8). This round: revert to r8 gather (known 75us), drop redundant per-edge
// clamp (srclist pre-clamped at binning/fill), inline int64-detection into binning
// blocks (kills the detect_init dispatch on the binned path).

#define N_NODES 100000
#define N_EDGES 1600000
#define NBLK_N  391          // ceil(N_NODES/256)
#define NB      196          // buckets = ceil(N/512)
#define BKT_CAP 8960         // mean 8192 + ~8.5 sigma, overflow-guarded
#define BIN_GRID 391         // binning blocks, 4096 edges each
#define GEMM_GRID 1563       // ceil(N/64)

typedef unsigned int  u32;
typedef unsigned short u16;
typedef unsigned char u8;
typedef unsigned long long u64;
typedef __attribute__((ext_vector_type(8))) short bf16x8;
typedef __attribute__((ext_vector_type(4))) float f32x4;

__device__ __forceinline__ float bflo(u32 u){ return __uint_as_float(u << 16); }
__device__ __forceinline__ float bfhi(u32 u){ return __uint_as_float(u & 0xFFFF0000u); }
__device__ __forceinline__ u32 f2b(float f){
  u32 u = __float_as_uint(f);
  return (u + 0x7FFFu + ((u >> 16) & 1u)) >> 16;   // RNE
}
__device__ __forceinline__ u32 pack2(float a, float b){ return f2b(a) | (f2b(b) << 16); }
__device__ __forceinline__ u32 clampN(int s){
  u32 u = (u32)s;
  return (u < (u32)N_NODES) ? u : (u32)(N_NODES - 1);
}

// ---------------- detect (fallback path only) ----------------
__global__ __launch_bounds__(64) void detect(const int* __restrict__ ei,
                                             int* __restrict__ flags){
  int l = threadIdx.x;
  int nzodd = (ei[2 * l + 1] != 0) ? 1 : 0;
  #pragma unroll
  for (int o = 32; o > 0; o >>= 1) nzodd += __shfl_xor(nzodd, o, 64);
  if (l == 0) flags[1] = (nzodd == 0) ? 1 : 0;   // 1 => int64
}

// ---------------- GEMM device bodies (16x16x32 bf16 MFMA, bf16 H output) ----------------
// A-frag: m=lane&15, k=(lane>>4)*8+j   B-frag: n=lane&15, k=(lane>>4)*8+j
// D: col=lane&15, row=(lane>>4)*4+r.  W (fp32) -> bf16 fragment-major LDS.

__device__ __forceinline__ void build_wfrag(u16* wfrag, const float* __restrict__ W,
                                            int tid){
  #pragma unroll
  for (int i = 0; i < 8; ++i){
    int fid   = tid + i * 256;
    int lane  = fid & 63;
    int kb    = (fid >> 6) & 3;
    int ntile = fid >> 8;
    int n  = ntile * 16 + (lane & 15);
    int k0 = kb * 32 + (lane >> 4) * 8;
    u16 tmp[8];
    #pragma unroll
    for (int j = 0; j < 8; ++j) tmp[j] = (u16)f2b(W[(k0 + j) * 128 + n]);
    *(bf16x8*)(wfrag + (size_t)fid * 8) = *(const bf16x8*)tmp;
  }
}

__device__ __forceinline__ void gemm_tail(const u16* wfrag, const bf16x8 afrag[4],
                                          int rowbase, int lane,
                                          u16* __restrict__ Hout, int nrows){
  const int m = lane & 15, q = lane >> 4;
  f32x4 acc[8];
  #pragma unroll
  for (int n = 0; n < 8; ++n) acc[n] = (f32x4){0.f, 0.f, 0.f, 0.f};
  #pragma unroll
  for (int n = 0; n < 8; ++n){
    #pragma unroll
    for (int kb = 0; kb < 4; ++kb){
      bf16x8 bfrag = *(const bf16x8*)(wfrag + ((size_t)(n * 4 + kb) * 64 + lane) * 8);
      acc[n] = __builtin_amdgcn_mfma_f32_16x16x32_bf16(afrag[kb], bfrag, acc[n], 0, 0, 0);
    }
  }
  #pragma unroll
  for (int r = 0; r < 4; ++r){
    int orow = rowbase + q * 4 + r;
    if (orow < nrows){
      u16* Or = Hout + (size_t)orow * 128 + m;
      #pragma unroll
      for (int n = 0; n < 8; ++n) Or[n * 16] = (u16)f2b(acc[n][r]);
    }
  }
}

__device__ __forceinline__ void gemm_f32_body(u16* wfrag, const float* __restrict__ A,
                                              const float* __restrict__ W,
                                              u16* __restrict__ Hout, int nrows, int bid){
  build_wfrag(wfrag, W, threadIdx.x);
  __syncthreads();
  const int lane = threadIdx.x & 63;
  const int wv   = threadIdx.x >> 6;
  const int rowbase = bid * 64 + wv * 16;
  const int row  = rowbase + (lane & 15);
  const int rowc = (row < nrows) ? row : (nrows - 1);
  const int q    = lane >> 4;
  bf16x8 afrag[4];
  const float* Ar = A + (size_t)rowc * 128;
  #pragma unroll
  for (int kb = 0; kb < 4; ++kb){
    f32x4 p0 = *(const f32x4*)(Ar + kb * 32 + q * 8);
    f32x4 p1 = *(const f32x4*)(Ar + kb * 32 + q * 8 + 4);
    bf16x8 f;
    f[0] = (short)f2b(p0[0]); f[1] = (short)f2b(p0[1]);
    f[2] = (short)f2b(p0[2]); f[3] = (short)f2b(p0[3]);
    f[4] = (short)f2b(p1[0]); f[5] = (short)f2b(p1[1]);
    f[6] = (short)f2b(p1[2]); f[7] = (short)f2b(p1[3]);
    afrag[kb] = f;
  }
  gemm_tail(wfrag, afrag, rowbase, lane, Hout, nrows);
}

__device__ __forceinline__ void gemm_bf16_body(u16* wfrag, const u16* __restrict__ A,
                                               const float* __restrict__ W,
                                               u16* __restrict__ Hout, int nrows, int bid){
  build_wfrag(wfrag, W, threadIdx.x);
  __syncthreads();
  const int lane = threadIdx.x & 63;
  const int wv   = threadIdx.x >> 6;
  const int rowbase = bid * 64 + wv * 16;
  const int row  = rowbase + (lane & 15);
  const int rowc = (row < nrows) ? row : (nrows - 1);
  const int q    = lane >> 4;
  bf16x8 afrag[4];
  const u16* Ar = A + (size_t)rowc * 128;
  #pragma unroll
  for (int kb = 0; kb < 4; ++kb)
    afrag[kb] = *(const bf16x8*)(Ar + kb * 32 + q * 8);
  gemm_tail(wfrag, afrag, rowbase, lane, Hout, nrows);
}

// ---------------- binning body: edges -> per-bucket-contiguous packed buffer ----------------
// int64-vs-int32 edge width detected INLINE (odd i32 words of int64 ids are all 0);
// broadcast through LDS, folded into the existing barrier. No detect dispatch needed.

__device__ __forceinline__ void binA_body(u32* cnt /*LDS 512 u32 + 1 flag*/,
                                          const int* __restrict__ ei,
                                          u32* __restrict__ binned,
                                          u32* __restrict__ bucket_fill, int bb){
  u32* gbase = cnt + 256;
  u32* flagp = cnt + 512;
  const int tid = threadIdx.x;
  cnt[tid] = 0;
  if (tid < 64){
    int nz = (ei[2 * tid + 1] != 0) ? 1 : 0;
    u64 b = __ballot(nz);
    if (tid == 0) *flagp = (b == 0ull) ? 1u : 0u;   // 1 => int64
  }
  __syncthreads();
  const int i64  = (int)*flagp;
  const int base = bb * 4096;
  u32 pk[16], rk[16], bk[16];
  #pragma unroll
  for (int j = 0; j < 16; ++j){
    int e = base + tid + j * 256;
    bk[j] = 0xFFFFFFFFu;
    if (e < N_EDGES){
      int dsti = i64 ? ei[2 * N_EDGES + 2 * e] : ei[N_EDGES + e];
      int srci = i64 ? ei[2 * e]               : ei[e];
      u32 ud = clampN(dsti), us = clampN(srci);
      u32 b = ud >> 9;
      bk[j] = b;
      pk[j] = us | ((ud & 511u) << 17);
      rk[j] = atomicAdd(&cnt[b], 1u);
    }
  }
  __syncthreads();
  u32 c = cnt[tid];
  u32 old = 0;
  if (c) old = atomicAdd(&bucket_fill[tid < NB ? tid : 0], tid < NB ? c : 0u);
  gbase[tid] = old;
  __syncthreads();
  #pragma unroll
  for (int j = 0; j < 16; ++j){
    if (bk[j] != 0xFFFFFFFFu){
      u32 idx = gbase[bk[j]] + rk[j];
      if (idx < BKT_CAP) binned[(size_t)bk[j] * BKT_CAP + idx] = pk[j];
    }
  }
}

// ---------------- fused: gemm1 (blocks < GEMM_GRID) + binning (rest) ----------------

__global__ __launch_bounds__(256) void fused_gemm_bin(const float* __restrict__ A,
                                                      const float* __restrict__ W,
                                                      u16* __restrict__ Hout,
                                                      const int* __restrict__ ei,
                                                      u32* __restrict__ binned,
                                                      u32* __restrict__ bucket_fill){
  __shared__ u16 smem[16384];                  // 32 KB
  if (blockIdx.x < GEMM_GRID){
    gemm_f32_body(smem, A, W, Hout, N_NODES, blockIdx.x);
  } else {
    binA_body((u32*)smem, ei, binned, bucket_fill, blockIdx.x - GEMM_GRID);
  }
}

// standalone gemms (fallback path / layer 2)
__global__ __launch_bounds__(256) void gemm_f32in(const float* __restrict__ A,
                                                  const float* __restrict__ W,
                                                  u16* __restrict__ Hout){
  __shared__ u16 smem[16384];
  gemm_f32_body(smem, A, W, Hout, N_NODES, blockIdx.x);
}
__global__ __launch_bounds__(256) void gemm_bf16in(const u16* __restrict__ A,
                                                   const float* __restrict__ W,
                                                   u16* __restrict__ Hout){
  __shared__ u16 smem[16384];
  gemm_bf16_body(smem, A, W, Hout, N_NODES, blockIdx.x);
}

// ---------------- fill_sort: one block per bucket (offs + dinv + sorted srclist) ----------------

__global__ __launch_bounds__(256) void fill_sort(const u32* __restrict__ binned,
                                                 const u32* __restrict__ bucket_fill,
                                                 int* __restrict__ offs,
                                                 float* __restrict__ dinv,
                                                 int* __restrict__ srclist){
  __shared__ u32 cnt[512];
  __shared__ u32 sc[512];
  __shared__ u32 red[256];
  const int b   = blockIdx.x;
  const int tid = threadIdx.x;
  cnt[tid] = 0; cnt[tid + 256] = 0;
  __syncthreads();

  u32 n = bucket_fill[b]; if (n > BKT_CAP) n = BKT_CAP;
  const u32* eb = binned + (size_t)b * BKT_CAP;

  for (u32 i = tid; i < n; i += 256)
    atomicAdd(&cnt[eb[i] >> 17], 1u);

  u32 v = 0;
  if (tid < b && tid < NB){
    u32 f = bucket_fill[tid];
    v = (f > BKT_CAP) ? BKT_CAP : f;
  }
  red[tid] = v;
  __syncthreads();
  for (int o = 128; o > 0; o >>= 1){
    if (tid < o) red[tid] += red[tid + o];
    __syncthreads();
  }
  const u32 base = red[0];
  __syncthreads();

  u32 pair = cnt[2 * tid] + cnt[2 * tid + 1];
  red[tid] = pair;
  __syncthreads();
  for (int o = 1; o < 256; o <<= 1){
    u32 add = (tid >= o) ? red[tid - o] : 0;
    __syncthreads();
    red[tid] += add;
    __syncthreads();
  }
  u32 pex = red[tid] - pair;
  sc[2 * tid]     = pex;
  sc[2 * tid + 1] = pex + cnt[2 * tid];
  __syncthreads();

  const u32 basenode = (u32)b << 9;
  #pragma unroll
  for (int h = 0; h < 2; ++h){
    u32 l = tid + h * 256;
    u32 node = basenode + l;
    if (node < (u32)N_NODES){
      offs[node] = (int)(base + sc[l]);
      dinv[node] = rsqrtf((float)cnt[l] + 1.0f);
    }
  }
  if (b == NB - 1 && tid == 0) offs[N_NODES] = (int)(base + n);

  __syncthreads();
  cnt[tid] = 0; cnt[tid + 256] = 0;
  __syncthreads();
  for (u32 i = tid; i < n; i += 256){
    u32 pk = eb[i];
    u32 d  = pk >> 17;
    u32 r  = atomicAdd(&cnt[d], 1u);
    srclist[base + sc[d] + r] = (int)(pk & 0x1FFFFu);   // value < N (clamped at pack)
  }
}

// ---------------- fallback CSR kernels (round-5 path, used if ws too small) ----------------

__global__ __launch_bounds__(256) void count_deg(const int* __restrict__ ei,
                                                 const int* __restrict__ flags,
                                                 int* __restrict__ deg){
  int e   = blockIdx.x * 256 + threadIdx.x;
  int i64 = flags[1];
  int dst = i64 ? ei[2 * N_EDGES + 2 * e] : ei[N_EDGES + e];
  if ((unsigned)dst < (unsigned)N_NODES) atomicAdd(&deg[dst], 1);
}

__global__ __launch_bounds__(256) void fill_edges(const int* __restrict__ ei,
                                                  const int* __restrict__ flags,
                                                  int* __restrict__ woff,
                                                  int* __restrict__ srclist){
  int e   = blockIdx.x * 256 + threadIdx.x;
  int i64 = flags[1];
  int dst = i64 ? ei[2 * N_EDGES + 2 * e] : ei[N_EDGES + e];
  int src = i64 ? ei[2 * e]               : ei[e];
  if ((unsigned)dst < (unsigned)N_NODES){
    int p = atomicAdd(&woff[dst], 1);
    if ((unsigned)p < (unsigned)N_EDGES) srclist[p] = clampN(src);  // keep < N for gathers
  }
}

__global__ __launch_bounds__(256) void scan1(const int* __restrict__ deg,
                                             int* __restrict__ offs,
                                             int* __restrict__ bsum,
                                             float* __restrict__ dinv){
  __shared__ int sh[256];
  int t = threadIdx.x;
  int i = blockIdx.x * 256 + t;
  int v = (i < N_NODES) ? deg[i] : 0;
  if (i < N_NODES) dinv[i] = rsqrtf((float)v + 1.0f);
  sh[t] = v;
  __syncthreads();
  for (int o = 1; o < 256; o <<= 1){
    int add = (t >= o) ? sh[t - o] : 0;
    __syncthreads();
    sh[t] += add;
    __syncthreads();
  }
  if (i < N_NODES) offs[i] = sh[t] - v;
  if (t == 255)    bsum[blockIdx.x] = sh[255];
}

__global__ __launch_bounds__(512) void scan2(const int* __restrict__ bsum,
                                             int* __restrict__ bofs){
  __shared__ int sh[512];
  int t = threadIdx.x;
  int v = (t < NBLK_N) ? bsum[t] : 0;
  sh[t] = v;
  __syncthreads();
  for (int o = 1; o < 512; o <<= 1){
    int add = (t >= o) ? sh[t - o] : 0;
    __syncthreads();
    sh[t] += add;
    __syncthreads();
  }
  if (t < NBLK_N) bofs[t] = sh[t] - v;
}

__global__ __launch_bounds__(256) void finalize_offs(int* __restrict__ offs,
                                                     const int* __restrict__ bofs,
                                                     int* __restrict__ woff){
  int i = blockIdx.x * 256 + threadIdx.x;
  if (i < N_NODES){
    int o = offs[i] + bofs[blockIdx.x];
    offs[i] = o;
    woff[i] = o;
  }
  if (i == 0) offs[N_NODES] = N_EDGES;
}

// ---------------- gathers (r8 structure): 1 wave/node, 2 cols/lane, 8-edge MLP ----------------
// srclist entries are guaranteed < N (clamped at binning / fallback fill) -> no per-edge clamp.

#define GATHER_EDGE(sv, A0, A1)                         \
  { u32 s_ = (u32)(sv);                                 \
    float w_ = dinv[s_];                                \
    u32 h_ = H[s_ * 64 + lane];                         \
    A0 = fmaf(w_, bflo(h_), A0);                        \
    A1 = fmaf(w_, bfhi(h_), A1); }

__global__ __launch_bounds__(256) void gather_relu(const int* __restrict__ offs,
                                                   const int* __restrict__ srcl,
                                                   const u32* __restrict__ H,
                                                   const float* __restrict__ dinv,
                                                   const float* __restrict__ bias,
                                                   u32* __restrict__ X2){
  const int node = blockIdx.x * 4 + (threadIdx.x >> 6);
  const int lane = threadIdx.x & 63;
  int beg = offs[node], end = offs[node + 1];
  if (end > N_EDGES) end = N_EDGES;
  if (beg < 0 || beg > end) beg = end;
  float a0 = 0.f, a1 = 0.f, c0 = 0.f, c1 = 0.f;
  int e = beg;
  for (; e + 8 <= end; e += 8){
    int s0=srcl[e],s1=srcl[e+1],s2=srcl[e+2],s3=srcl[e+3];
    int s4=srcl[e+4],s5=srcl[e+5],s6=srcl[e+6],s7=srcl[e+7];
    GATHER_EDGE(s0,a0,a1) GATHER_EDGE(s1,c0,c1)
    GATHER_EDGE(s2,a0,a1) GATHER_EDGE(s3,c0,c1)
    GATHER_EDGE(s4,a0,a1) GATHER_EDGE(s5,c0,c1)
    GATHER_EDGE(s6,a0,a1) GATHER_EDGE(s7,c0,c1)
  }
  for (; e + 4 <= end; e += 4){
    int s0=srcl[e],s1=srcl[e+1],s2=srcl[e+2],s3=srcl[e+3];
    GATHER_EDGE(s0,a0,a1) GATHER_EDGE(s1,c0,c1)
    GATHER_EDGE(s2,a0,a1) GATHER_EDGE(s3,c0,c1)
  }
  for (; e < end; ++e){ int s0=srcl[e]; GATHER_EDGE(s0,a0,a1) }
  a0 += c0;  a1 += c1;
  float di = dinv[node];
  u32 hs = H[(u32)node * 64 + lane];
  float b0 = bias[2 * lane], b1v = bias[2 * lane + 1];
  float v0 = fmaf(a0, di, fmaf(bflo(hs), di * di, b0));
  float v1 = fmaf(a1, di, fmaf(bfhi(hs), di * di, b1v));
  X2[(u32)node * 64 + lane] = pack2(fmaxf(v0, 0.f), fmaxf(v1, 0.f));
}

__global__ __launch_bounds__(256) void gather_ln(const int* __restrict__ offs,
                                                 const int* __restrict__ srcl,
                                                 const u32* __restrict__ H,
                                                 const float* __restrict__ dinv,
                                                 const float* __restrict__ bias,
                                                 const float* __restrict__ gamma,
                                                 const float* __restrict__ beta,
                                                 float* __restrict__ out){
  const int node = blockIdx.x * 4 + (threadIdx.x >> 6);
  const int lane = threadIdx.x & 63;
  int beg = offs[node], end = offs[node + 1];
  if (end > N_EDGES) end = N_EDGES;
  if (beg < 0 || beg > end) beg = end;
  float a0 = 0.f, a1 = 0.f, c0 = 0.f, c1 = 0.f;
  int e = beg;
  for (; e + 8 <= end; e += 8){
    int s0=srcl[e],s1=srcl[e+1],s2=srcl[e+2],s3=srcl[e+3];
    int s4=srcl[e+4],s5=srcl[e+5],s6=srcl[e+6],s7=srcl[e+7];
    GATHER_EDGE(s0,a0,a1) GATHER_EDGE(s1,c0,c1)
    GATHER_EDGE(s2,a0,a1) GATHER_EDGE(s3,c0,c1)
    GATHER_EDGE(s4,a0,a1) GATHER_EDGE(s5,c0,c1)
    GATHER_EDGE(s6,a0,a1) GATHER_EDGE(s7,c0,c1)
  }
  for (; e + 4 <= end; e += 4){
    int s0=srcl[e],s1=srcl[e+1],s2=srcl[e+2],s3=srcl[e+3];
    GATHER_EDGE(s0,a0,a1) GATHER_EDGE(s1,c0,c1)
    GATHER_EDGE(s2,a0,a1) GATHER_EDGE(s3,c0,c1)
  }
  for (; e < end; ++e){ int s0=srcl[e]; GATHER_EDGE(s0,a0,a1) }
  a0 += c0;  a1 += c1;
  float di = dinv[node];
  u32 hs = H[(u32)node * 64 + lane];
  float b0 = bias[2 * lane], b1v = bias[2 * lane + 1];
  float v0 = fmaf(a0, di, fmaf(bflo(hs), di * di, b0));
  float v1 = fmaf(a1, di, fmaf(bfhi(hs), di * di, b1v));

  float s2 = v0 + v1;
  #pragma unroll
  for (int o = 32; o > 0; o >>= 1) s2 += __shfl_xor(s2, o, 64);
  float mu = s2 * 0.0078125f;
  float d0 = v0 - mu, d1 = v1 - mu;
  float qq = d0 * d0 + d1 * d1;
  #pragma unroll
  for (int o = 32; o > 0; o >>= 1) qq += __shfl_xor(qq, o, 64);
  float rr = rsqrtf(qq * 0.0078125f + 1e-5f);

  float g0 = gamma[2 * lane], g1 = gamma[2 * lane + 1];
  float t0 = beta[2 * lane],  t1 = beta[2 * lane + 1];
  *(float2*)(out + (size_t)node * 128 + 2 * lane) =
      make_float2(fmaf(d0 * rr, g0, t0), fmaf(d1 * rr, g1, t1));
}

// ---------------- launch ----------------

extern "C" void kernel_launch(void* const* d_in, const int* in_sizes, int n_in,
                              void* d_out, int out_size, void* d_ws, size_t ws_size,
                              hipStream_t stream){
  const float* x  = (const float*)d_in[0];
  const int*   ei = (const int*)d_in[1];
  const float* W1 = (const float*)d_in[2];
  const float* b1 = (const float*)d_in[3];
  const float* W2 = (const float*)d_in[4];
  const float* b2 = (const float*)d_in[5];
  const float* gm = (const float*)d_in[6];
  const float* bt = (const float*)d_in[7];

  char* ws = (char*)d_ws;
  size_t off = 0;
  auto carve = [&](size_t bytes) -> void* {
    void* p = ws + off;
    off = (off + bytes + 255) & ~(size_t)255;
    return p;
  };
  int*   flags       = (int*)  carve(64);
  u32*   bucket_fill = (u32*)  carve(NB * 4);
  int*   offs        = (int*)  carve((size_t)(N_NODES + 1) * 4);
  float* dinv        = (float*)carve((size_t)N_NODES * 4);
  int*   srclist     = (int*)  carve((size_t)N_EDGES * 4);
  int*   deg         = (int*)  carve((size_t)N_NODES * 4);   // fallback only (woff)
  int*   bsum        = (int*)  carve(2048);                  // fallback only
  int*   bofs        = (int*)  carve(2048);                  // fallback only

  size_t bin_bytes = (size_t)NB * BKT_CAP * 4;               // 7.02 MB
  u32* binned = (u32*)carve(bin_bytes);
  bool use_binned = (ws_size >= off);
  if (!use_binned) off = (size_t)((char*)binned - ws);       // un-carve

  size_t h_bytes = (size_t)N_NODES * 128 * 2;                // 25.6 MB (bf16)
  u32* H1 = (u32*)d_out;
  u32* X2 = (u32*)d_out + 6400000;
  u32* H2 = (ws_size >= off + h_bytes) ? (u32*)carve(h_bytes) : (u32*)d_in[0];

  if (use_binned){
    hipMemsetAsync(bucket_fill, 0, NB * 4, stream);
    fused_gemm_bin<<<GEMM_GRID + BIN_GRID, 256, 0, stream>>>(x, W1, (u16*)H1, ei,
                                                             binned, bucket_fill);
    fill_sort     <<<NB, 256, 0, stream>>>(binned, bucket_fill, offs, dinv, srclist);
  } else {
    hipMemsetAsync(deg, 0, (size_t)N_NODES * 4, stream);
    detect        <<<1,             64,  0, stream>>>(ei, flags);
    count_deg     <<<N_EDGES / 256, 256, 0, stream>>>(ei, flags, deg);
    scan1         <<<NBLK_N,        256, 0, stream>>>(deg, offs, bsum, dinv);
    scan2         <<<1,             512, 0, stream>>>(bsum, bofs);
    finalize_offs <<<NBLK_N,        256, 0, stream>>>(offs, bofs, deg /*woff*/);
    fill_edges    <<<N_EDGES / 256, 256, 0, stream>>>(ei, flags, deg /*woff*/, srclist);
    gemm_f32in    <<<GEMM_GRID,     256, 0, stream>>>(x, W1, (u16*)H1);
  }

  gather_relu <<<N_NODES / 4, 256, 0, stream>>>(offs, srclist, H1, dinv, b1, X2);
  gemm_bf16in <<<GEMM_GRID,   256, 0, stream>>>((const u16*)X2, W2, (u16*)H2);
  gather_ln   <<<N_NODES / 4, 256, 0, stream>>>(offs, srclist, H2, dinv, b2, gm, bt,
                                                (float*)d_out);
}